// Round 14
// baseline (438.205 us; speedup 1.0000x reference)
//
#include <hip/hip_runtime.h>
#include <hip/hip_bf16.h>
#include <cstdint>
#include <cstddef>

#define NN 50000
#define NE 400000
typedef long long i64;
typedef unsigned short u16;
typedef __attribute__((ext_vector_type(8))) short bf16x8;
typedef __attribute__((ext_vector_type(8))) unsigned short u16x8;
typedef __attribute__((ext_vector_type(4))) unsigned short u16x4;
typedef __attribute__((ext_vector_type(4))) float f32x4;

__device__ inline u16 f2bf(float f) {  // RNE
    unsigned u = __float_as_uint(f);
    u += 0x7fffu + ((u >> 16) & 1u);
    return (u16)(u >> 16);
}
__device__ inline float bf2f(u16 b) { return __uint_as_float(((unsigned)b) << 16); }

// ---------------- setup kernels ----------------
__global__ void k_detect(const void* __restrict__ ei, int* __restrict__ flag) {
    int i = blockIdx.x * blockDim.x + threadIdx.x;
    if (i < NE) {
        i64 v = ((const i64*)ei)[i];
        if (v < 0 || v >= NN) atomicOr(flag, 1);
    }
}

__device__ inline int edge_at(const void* ei, int f32idx, int half, int i) {
    if (f32idx) return ((const int*)ei)[half * NE + i];
    return (int)((const i64*)ei)[half * NE + i];
}

__global__ void k_hist(const void* __restrict__ ei, const int* __restrict__ flag,
                       int* __restrict__ deg) {
    int i = blockIdx.x * blockDim.x + threadIdx.x;
    if (i < NE) {
        int d = edge_at(ei, *flag, 1, i);
        if ((unsigned)d < NN) atomicAdd(&deg[d], 1);
    }
}

// ---------------- 3-phase parallel scan (scan1 also does node_setup) ----------------
#define SB 256
#define NBLK ((NN + SB - 1) / SB)  // 196

__global__ __launch_bounds__(SB) void k_scan1(const int* __restrict__ deg,
                                              int* __restrict__ excl,
                                              int* __restrict__ bsum,
                                              float* __restrict__ inv_sqrt,
                                              float* __restrict__ inv_deg) {
    __shared__ int s[SB];
    int t = threadIdx.x;
    int i = blockIdx.x * SB + t;
    int v = (i < NN) ? deg[i] : 0;
    if (i < NN) {
        float d = (float)v + 1.0f;
        inv_sqrt[i] = rsqrtf(d);
        inv_deg[i]  = 1.0f / d;
    }
    s[t] = v;
    __syncthreads();
    for (int off = 1; off < SB; off <<= 1) {
        int x = (t >= off) ? s[t - off] : 0;
        __syncthreads();
        s[t] += x;
        __syncthreads();
    }
    if (i < NN) excl[i] = s[t] - v;
    if (t == SB - 1) bsum[blockIdx.x] = s[t];
}

__global__ __launch_bounds__(SB) void k_scan2(int* __restrict__ bsum) {
    __shared__ int s[SB];
    int t = threadIdx.x;
    int v = (t < NBLK) ? bsum[t] : 0;
    s[t] = v;
    __syncthreads();
    for (int off = 1; off < SB; off <<= 1) {
        int x = (t >= off) ? s[t - off] : 0;
        __syncthreads();
        s[t] += x;
        __syncthreads();
    }
    if (t < NBLK) bsum[t] = s[t] - v;
    if (t == NBLK - 1) bsum[NBLK] = s[t];
}

__global__ __launch_bounds__(SB) void k_scan3(int* __restrict__ row_off,
                                              int* __restrict__ cursor,
                                              const int* __restrict__ bsum) {
    int i = blockIdx.x * SB + threadIdx.x;
    if (i < NN) {
        int r = row_off[i] + bsum[blockIdx.x];
        row_off[i] = r;
        cursor[i]  = r;
    }
    if (i == 0) row_off[NN] = bsum[NBLK];
}

__global__ void k_scatter(const void* __restrict__ ei, const int* __restrict__ flag,
                          const float* __restrict__ inv_sqrt,
                          int* __restrict__ cursor, int* __restrict__ ssrc,
                          float* __restrict__ snorm) {
    int i = blockIdx.x * blockDim.x + threadIdx.x;
    if (i < NE) {
        int f = *flag;
        int s = edge_at(ei, f, 0, i);
        int d = edge_at(ei, f, 1, i);
        if ((unsigned)s < NN && (unsigned)d < NN) {
            int pos = atomicAdd(&cursor[d], 1);
            if ((unsigned)pos < NE) {
                ssrc[pos]  = s;
                snorm[pos] = inv_sqrt[s] * inv_sqrt[d];
            }
        }
    }
}

// ---------------- merged prep: 3x weight transpose (f32->bf16, coalesced) + x->bf16 ----------------
#define PREP_BLOCKS 6954
__global__ __launch_bounds__(256) void k_prep(const float* __restrict__ W1, u16* __restrict__ Wt1,
                                              const float* __restrict__ W2, u16* __restrict__ Wt2,
                                              const float* __restrict__ W3, u16* __restrict__ Wt3,
                                              const float* __restrict__ x, u16* __restrict__ xb) {
    __shared__ u16 tile[32][33];
    int b = blockIdx.x;
    if (b < 704) {
        const float* W; u16* Wt; int K, N, base;
        if (b < 128)      { W = W1; Wt = Wt1; K = 128;  N = 1024; base = 0; }
        else if (b < 640) { W = W2; Wt = Wt2; K = 1024; N = 512;  base = 128; }
        else              { W = W3; Wt = Wt3; K = 512;  N = 128;  base = 640; }
        int bb = b - base;
        int ntk = K >> 5;
        int tk = bb % ntk, tn = bb / ntk;
        int lx = threadIdx.x & 31, ly = threadIdx.x >> 5;
#pragma unroll
        for (int r = 0; r < 32; r += 8)
            tile[ly + r][lx] = f2bf(W[(size_t)(tk * 32 + ly + r) * N + tn * 32 + lx]);
        __syncthreads();
#pragma unroll
        for (int r = 0; r < 32; r += 8)
            Wt[(size_t)(tn * 32 + ly + r) * K + tk * 32 + lx] = tile[lx][ly + r];
    } else {
        int i = (b - 704) * 256 + threadIdx.x;
        if (i < NN * 128 / 4) {
            float4 v = ((const float4*)x)[i];
            u16x4 r;
            r[0] = f2bf(v.x); r[1] = f2bf(v.y); r[2] = f2bf(v.z); r[3] = f2bf(v.w);
            ((u16x4*)xb)[i] = r;
        }
    }
}

// ---------------- CSR aggregation (bf16 in), 4-way edge-unrolled ----------------
template <int W, int TOUT, bool BIAS, bool RELU>
__global__ __launch_bounds__(64) void k_agg(const u16* __restrict__ X, void* __restrict__ Yv,
                      const int* __restrict__ row_off, const int* __restrict__ ssrc,
                      const float* __restrict__ snorm, const float* __restrict__ inv_deg,
                      const float* __restrict__ bias) {
    constexpr int E = W / 64;
    int node = blockIdx.x;
    int lane = threadIdx.x;
    int col = lane * E;
    int beg = row_off[node], end = row_off[node + 1];
    float acc[E];
#pragma unroll
    for (int v = 0; v < E; v++) acc[v] = 0.f;

    auto rowp = [&](int srow) -> const u16* {
        unsigned s = (unsigned)srow;
        if (s >= NN) s = 0;
        return X + (size_t)s * W + col;
    };
    auto fma8 = [&](u16x8 t, float w) {
#pragma unroll
        for (int j = 0; j < 8; j++) acc[j] = fmaf(bf2f(t[j]), w, acc[j]);
    };
    auto fma2 = [&](unsigned t, float w) {
        acc[0] = fmaf(bf2f((u16)(t & 0xffff)), w, acc[0]);
        acc[1] = fmaf(bf2f((u16)(t >> 16)), w, acc[1]);
    };

    int e = beg;
    for (; e + 3 < end; e += 4) {
        int s0 = ssrc[e], s1 = ssrc[e + 1], s2 = ssrc[e + 2], s3 = ssrc[e + 3];
        float w0 = snorm[e], w1 = snorm[e + 1], w2 = snorm[e + 2], w3 = snorm[e + 3];
        w0 = ((unsigned)s0 < NN) ? w0 : 0.f;
        w1 = ((unsigned)s1 < NN) ? w1 : 0.f;
        w2 = ((unsigned)s2 < NN) ? w2 : 0.f;
        w3 = ((unsigned)s3 < NN) ? w3 : 0.f;
        if constexpr (E == 2) {
            unsigned t0 = *(const unsigned*)rowp(s0);
            unsigned t1 = *(const unsigned*)rowp(s1);
            unsigned t2 = *(const unsigned*)rowp(s2);
            unsigned t3 = *(const unsigned*)rowp(s3);
            fma2(t0, w0); fma2(t1, w1); fma2(t2, w2); fma2(t3, w3);
        } else {
            u16x8 t0 = *(const u16x8*)rowp(s0);
            u16x8 t1 = *(const u16x8*)rowp(s1);
            u16x8 t2 = *(const u16x8*)rowp(s2);
            u16x8 t3 = *(const u16x8*)rowp(s3);
            fma8(t0, w0); fma8(t1, w1); fma8(t2, w2); fma8(t3, w3);
        }
    }
    for (; e < end; e++) {
        int s = ssrc[e];
        if ((unsigned)s >= NN) continue;
        float w = snorm[e];
        if constexpr (E == 2) fma2(*(const unsigned*)rowp(s), w);
        else                  fma8(*(const u16x8*)rowp(s), w);
    }
    {   // self-loop
        float w = inv_deg[node];
        if constexpr (E == 2) fma2(*(const unsigned*)(X + (size_t)node * W + col), w);
        else                  fma8(*(const u16x8*)(X + (size_t)node * W + col), w);
    }

#pragma unroll
    for (int v = 0; v < E; v++) {
        float val = acc[v];
        if (BIAS) val += bias[col + v];
        if (RELU) val = fmaxf(val, 0.f);
        if constexpr (TOUT == 0) ((float*)Yv)[(size_t)node * W + col + v] = val;
        else ((u16*)Yv)[(size_t)node * W + col + v] = f2bf(val);
    }
}

// ---------------- final aggregation + fused FC (4-way unrolled) ----------------
__global__ __launch_bounds__(64) void k_agg_fc(const u16* __restrict__ X,
                      float* __restrict__ out,
                      const int* __restrict__ row_off, const int* __restrict__ ssrc,
                      const float* __restrict__ snorm, const float* __restrict__ inv_deg,
                      const float* __restrict__ b3, const float* __restrict__ Wfc,
                      const float* __restrict__ bfc) {
    __shared__ float hrow[128];
    int node = blockIdx.x;
    int lane = threadIdx.x;
    int col = lane * 2;
    int beg = row_off[node], end = row_off[node + 1];
    float a0 = 0.f, a1 = 0.f;

    auto rowu = [&](int srow) -> unsigned {
        unsigned s = (unsigned)srow;
        if (s >= NN) s = 0;
        return *(const unsigned*)(X + (size_t)s * 128 + col);
    };
    int e = beg;
    for (; e + 3 < end; e += 4) {
        int s0 = ssrc[e], s1 = ssrc[e + 1], s2 = ssrc[e + 2], s3 = ssrc[e + 3];
        float w0 = snorm[e], w1 = snorm[e + 1], w2 = snorm[e + 2], w3 = snorm[e + 3];
        w0 = ((unsigned)s0 < NN) ? w0 : 0.f;
        w1 = ((unsigned)s1 < NN) ? w1 : 0.f;
        w2 = ((unsigned)s2 < NN) ? w2 : 0.f;
        w3 = ((unsigned)s3 < NN) ? w3 : 0.f;
        unsigned t0 = rowu(s0), t1 = rowu(s1), t2 = rowu(s2), t3 = rowu(s3);
        a0 = fmaf(bf2f((u16)(t0 & 0xffff)), w0, a0); a1 = fmaf(bf2f((u16)(t0 >> 16)), w0, a1);
        a0 = fmaf(bf2f((u16)(t1 & 0xffff)), w1, a0); a1 = fmaf(bf2f((u16)(t1 >> 16)), w1, a1);
        a0 = fmaf(bf2f((u16)(t2 & 0xffff)), w2, a0); a1 = fmaf(bf2f((u16)(t2 >> 16)), w2, a1);
        a0 = fmaf(bf2f((u16)(t3 & 0xffff)), w3, a0); a1 = fmaf(bf2f((u16)(t3 >> 16)), w3, a1);
    }
    for (; e < end; e++) {
        int s = ssrc[e];
        if ((unsigned)s >= NN) continue;
        float w = snorm[e];
        unsigned t = *(const unsigned*)(X + (size_t)s * 128 + col);
        a0 = fmaf(bf2f((u16)(t & 0xffff)), w, a0);
        a1 = fmaf(bf2f((u16)(t >> 16)), w, a1);
    }
    {
        float w = inv_deg[node];
        unsigned t = *(const unsigned*)(X + (size_t)node * 128 + col);
        a0 = fmaf(bf2f((u16)(t & 0xffff)), w, a0);
        a1 = fmaf(bf2f((u16)(t >> 16)), w, a1);
    }
    hrow[col]     = fmaxf(a0 + b3[col], 0.f);
    hrow[col + 1] = fmaxf(a1 + b3[col + 1], 0.f);
    __syncthreads();
    if (lane < 40) {
        float s = bfc[lane];
#pragma unroll 8
        for (int k = 0; k < 128; k++)
            s = fmaf(hrow[k], Wfc[k * 40 + lane], s);
        out[(size_t)node * 40 + lane] = s;
    }
}

#define LDS_AS(p) ((__attribute__((address_space(3))) void*)(p))
#define GLB_AS(p) ((const __attribute__((address_space(1))) void*)(p))
#define EPAD 68

// ---------------- 8-phase 256x256 bf16 MFMA GEMM (L1; grid 784 = 3.06 rounds) ----------------
template <bool BIAS, bool RELU>
__global__ __launch_bounds__(512, 2) void gemm8(
    const u16* __restrict__ A, const u16* __restrict__ Bt,
    const float* __restrict__ bias, u16* __restrict__ C,
    int M, int N, int K, int nbx) {
    __shared__ __align__(16) char smem[131072];
    char* buf0 = smem;
    char* buf1 = smem + 65536;
    const int tid = threadIdx.x;
    const int lane = tid & 63;
    const int wave = tid >> 6;
    const int wm = wave >> 2;  // 0..1
    const int wn = wave & 3;   // 0..3

    const int nwg = gridDim.x;
    int lg;
    { int q = nwg >> 3, r = nwg & 7, xc = blockIdx.x & 7, pos = blockIdx.x >> 3;
      lg = (xc < r ? xc * (q + 1) : r * (q + 1) + (xc - r) * q) + pos; }
    const int bm = (lg / nbx) * 256;
    const int bn = (lg % nbx) * 256;

    f32x4 acc[8][4];
#pragma unroll
    for (int m = 0; m < 8; m++)
#pragma unroll
        for (int n = 0; n < 4; n++) acc[m][n] = (f32x4)0.f;

    const int rb = tid >> 3;
    const int csw = ((tid & 7) ^ (rb & 7)) << 4;
    const int dstA = rb * 128 + (tid & 7) * 16;
    const size_t sK = (size_t)K * 2;
    const char* Ab = (const char*)A;
    const char* Bb = (const char*)Bt;
    size_t ga[2][2], gb[2][2];
#pragma unroll
    for (int h = 0; h < 2; h++)
#pragma unroll
        for (int j = 0; j < 2; j++) {
            int ar = bm + h * 128 + j * 64 + rb; if (ar >= M) ar = M - 1;
            int br = bn + h * 128 + j * 64 + rb;
            ga[h][j] = (size_t)ar * sK + csw;
            gb[h][j] = (size_t)br * sK + csw;
        }

    auto stA = [&](char* buf, size_t kb, int h) {
        __builtin_amdgcn_global_load_lds(GLB_AS(Ab + ga[h][0] + kb), LDS_AS(buf + h * 16384 + dstA), 16, 0, 0);
        __builtin_amdgcn_global_load_lds(GLB_AS(Ab + ga[h][1] + kb), LDS_AS(buf + h * 16384 + 8192 + dstA), 16, 0, 0);
    };
    auto stB = [&](char* buf, size_t kb, int h) {
        __builtin_amdgcn_global_load_lds(GLB_AS(Bb + gb[h][0] + kb), LDS_AS(buf + 32768 + h * 16384 + dstA), 16, 0, 0);
        __builtin_amdgcn_global_load_lds(GLB_AS(Bb + gb[h][1] + kb), LDS_AS(buf + 32768 + h * 16384 + 8192 + dstA), 16, 0, 0);
    };

    const int fr = lane & 15, g = lane >> 4;
    const int ksw0 = (((0 << 2) + g) ^ (fr & 7)) << 4;
    const int ksw1 = (((1 << 2) + g) ^ (fr & 7)) << 4;
    const int aRow = (wm * 128 + fr) * 128;
    const int bRow = 32768 + (wn * 64 + fr) * 128;

    bf16x8 af[4][2], bf[4][2];
    auto LDA = [&](const char* buf, int mg) {
#pragma unroll
        for (int m = 0; m < 4; m++) {
            af[m][0] = *(const bf16x8*)(buf + aRow + mg * 8192 + m * 2048 + ksw0);
            af[m][1] = *(const bf16x8*)(buf + aRow + mg * 8192 + m * 2048 + ksw1);
        }
    };
    auto LDB = [&](const char* buf, int ng) {
#pragma unroll
        for (int n = 0; n < 2; n++) {
            bf[ng * 2 + n][0] = *(const bf16x8*)(buf + bRow + (ng * 2 + n) * 2048 + ksw0);
            bf[ng * 2 + n][1] = *(const bf16x8*)(buf + bRow + (ng * 2 + n) * 2048 + ksw1);
        }
    };
    auto QMM = [&](int mg, int ng) {
        __builtin_amdgcn_s_setprio(1);
#pragma unroll
        for (int ks = 0; ks < 2; ks++)
#pragma unroll
            for (int m = 0; m < 4; m++)
#pragma unroll
                for (int n = 0; n < 2; n++)
                    acc[mg * 4 + m][ng * 2 + n] = __builtin_amdgcn_mfma_f32_16x16x32_bf16(
                        af[m][ks], bf[ng * 2 + n][ks], acc[mg * 4 + m][ng * 2 + n], 0, 0, 0);
        __builtin_amdgcn_s_setprio(0);
    };

#define BAR  __builtin_amdgcn_s_barrier()
#define LGKM do { asm volatile("s_waitcnt lgkmcnt(0)" ::: "memory"); __builtin_amdgcn_sched_barrier(0); } while (0)

    const int nit = K >> 7;

    stB(buf0, 0, 0); stB(buf0, 0, 1);
    stA(buf0, 0, 0); stA(buf0, 0, 1);
    stB(buf1, 128, 0); stB(buf1, 128, 1);
    asm volatile("s_waitcnt vmcnt(4)" ::: "memory");
    BAR;

    for (int it2 = 0; it2 < nit; ++it2) {
        const bool lastit = (it2 == nit - 1);
        const size_t kb = (size_t)it2 * 256;
        LDA(buf0, 0); LDB(buf0, 0);
        stA(buf1, kb + 128, 0);
        BAR; LGKM; QMM(0, 0); BAR;
        LDB(buf0, 1);
        stA(buf1, kb + 128, 1);
        BAR; LGKM; QMM(0, 1); BAR;
        LDA(buf0, 1);
        if (!lastit) stB(buf0, kb + 256, 0);
        BAR; LGKM; QMM(1, 0); BAR;
        if (!lastit) stB(buf0, kb + 256, 1);
        BAR; QMM(1, 1);
        if (lastit) asm volatile("s_waitcnt vmcnt(0)" ::: "memory");
        else        asm volatile("s_waitcnt vmcnt(4)" ::: "memory");
        BAR;
        LDA(buf1, 0); LDB(buf1, 0);
        if (!lastit) stA(buf0, kb + 256, 0);
        BAR; LGKM; QMM(0, 0); BAR;
        LDB(buf1, 1);
        if (!lastit) stA(buf0, kb + 256, 1);
        BAR; LGKM; QMM(0, 1); BAR;
        LDA(buf1, 1);
        if (!lastit) stB(buf1, kb + 384, 0);
        BAR; LGKM; QMM(1, 0); BAR;
        if (!lastit) stB(buf1, kb + 384, 1);
        BAR; QMM(1, 1);
        if (!lastit) asm volatile("s_waitcnt vmcnt(4)" ::: "memory");
        BAR;
    }

    u16* Es = (u16*)(smem + (size_t)wave * (64 * EPAD * 2));
    const int cr = (lane >> 4) << 2;
    const int cc = lane & 15;
    const int rl = lane >> 3;
    const int c8 = (lane & 7) * 8;
#pragma unroll
    for (int pass = 0; pass < 2; pass++) {
#pragma unroll
        for (int n = 0; n < 4; n++) {
            float bv = BIAS ? bias[bn + wn * 64 + n * 16 + cc] : 0.f;
#pragma unroll
            for (int m = 0; m < 4; m++) {
#pragma unroll
                for (int j = 0; j < 4; j++) {
                    float v = acc[pass * 4 + m][n][j] + bv;
                    if (RELU) v = fmaxf(v, 0.f);
                    Es[(m * 16 + cr + j) * EPAD + n * 16 + cc] = f2bf(v);
                }
            }
        }
#pragma unroll
        for (int itr = 0; itr < 8; itr++) {
            int lr = itr * 8 + rl;
            u16x8 vv = *(const u16x8*)(Es + lr * EPAD + c8);
            int grow = bm + wm * 128 + pass * 64 + lr;
            if (grow < M)
                *(u16x8*)(C + (size_t)grow * N + bn + wn * 64 + c8) = vv;
        }
    }
#undef BAR
#undef LGKM
}

// ---------------- 128x256 8-phase-style GEMM, 3-buffer LDS ring (L2) ----------------
// Halved M-tile kills the 392-block=1.53-round tail (782=3.05 rounds, ~2% waste).
// tile T lives in buf(T%3); T+2 staged during T's phases -> writer never touches
// a buffer being read (modulo-3 separation). Counted vmcnt(6) per tile boundary.
template <bool BIAS, bool RELU>
__global__ __launch_bounds__(512, 1) void gemm8h(
    const u16* __restrict__ A, const u16* __restrict__ Bt,
    const float* __restrict__ bias, u16* __restrict__ C,
    int M, int N, int K, int nbx) {
    __shared__ __align__(16) char smem[3 * 49152];  // 147456 B
    const int tid = threadIdx.x;
    const int lane = tid & 63;
    const int wave = tid >> 6;
    const int wm = wave >> 2;  // 0..1 (64-row halves of the 128-row tile)
    const int wn = wave & 3;   // 0..3

    const int nwg = gridDim.x;
    int lg;
    { int q = nwg >> 3, r = nwg & 7, xc = blockIdx.x & 7, pos = blockIdx.x >> 3;
      lg = (xc < r ? xc * (q + 1) : r * (q + 1) + (xc - r) * q) + pos; }
    const int bm = (lg / nbx) * 128;
    const int bn = (lg % nbx) * 256;

    f32x4 acc[4][4];
#pragma unroll
    for (int m = 0; m < 4; m++)
#pragma unroll
        for (int n = 0; n < 4; n++) acc[m][n] = (f32x4)0.f;

    const int rb = tid >> 3;
    const int csw = ((tid & 7) ^ (rb & 7)) << 4;
    const int dstA = rb * 128 + (tid & 7) * 16;
    const size_t sK = (size_t)K * 2;
    const char* Ab = (const char*)A;
    const char* Bb = (const char*)Bt;
    size_t ga[2], gb[4];
#pragma unroll
    for (int i = 0; i < 2; i++) {
        int ar = bm + rb + 64 * i; if (ar >= M) ar = M - 1;
        ga[i] = (size_t)ar * sK + csw;
    }
#pragma unroll
    for (int i = 0; i < 4; i++) {
        int br = bn + rb + 64 * i;  // N multiple of 256
        gb[i] = (size_t)br * sK + csw;
    }

    // per tile: 6 x 16B loads/thread -> B0(2), B1(2), A(2) in FIFO order
    auto stB01 = [&](int t) {
        char* buf = smem + (t % 3) * 49152;
        const size_t kb = (size_t)t * 128;
#pragma unroll
        for (int i = 0; i < 4; i++)
            __builtin_amdgcn_global_load_lds(GLB_AS(Bb + gb[i] + kb), LDS_AS(buf + 16384 + i * 8192 + dstA), 16, 0, 0);
    };
    auto stA2 = [&](int t) {
        char* buf = smem + (t % 3) * 49152;
        const size_t kb = (size_t)t * 128;
#pragma unroll
        for (int i = 0; i < 2; i++)
            __builtin_amdgcn_global_load_lds(GLB_AS(Ab + ga[i] + kb), LDS_AS(buf + i * 8192 + dstA), 16, 0, 0);
    };

    const int fr = lane & 15, g = lane >> 4;
    const int ksw0 = ((g) ^ (fr & 7)) << 4;
    const int ksw1 = ((4 + g) ^ (fr & 7)) << 4;
    const int aRow = (wm * 64 + fr) * 128;
    const int bRow = 16384 + (wn * 64 + fr) * 128;

    bf16x8 af[4][2], bf[2][2];
    auto LDA = [&](const char* buf) {
#pragma unroll
        for (int m = 0; m < 4; m++) {
            af[m][0] = *(const bf16x8*)(buf + aRow + m * 2048 + ksw0);
            af[m][1] = *(const bf16x8*)(buf + aRow + m * 2048 + ksw1);
        }
    };
    auto LDB = [&](const char* buf, int ng) {
#pragma unroll
        for (int n = 0; n < 2; n++) {
            bf[n][0] = *(const bf16x8*)(buf + bRow + (ng * 2 + n) * 2048 + ksw0);
            bf[n][1] = *(const bf16x8*)(buf + bRow + (ng * 2 + n) * 2048 + ksw1);
        }
    };
    auto QMM = [&](int ng) {
        __builtin_amdgcn_s_setprio(1);
#pragma unroll
        for (int ks = 0; ks < 2; ks++)
#pragma unroll
            for (int m = 0; m < 4; m++)
#pragma unroll
                for (int n = 0; n < 2; n++)
                    acc[m][ng * 2 + n] = __builtin_amdgcn_mfma_f32_16x16x32_bf16(
                        af[m][ks], bf[n][ks], acc[m][ng * 2 + n], 0, 0, 0);
        __builtin_amdgcn_s_setprio(0);
    };

#define BAR  __builtin_amdgcn_s_barrier()
#define LGKM do { asm volatile("s_waitcnt lgkmcnt(0)" ::: "memory"); __builtin_amdgcn_sched_barrier(0); } while (0)

    const int nt = K >> 6;  // K-tiles of 64; K % 64 == 0, nt >= 2

    // prologue: full T0 + T1 (12 loads); vmcnt(6) -> T0 landed, T1 in flight
    stB01(0); stA2(0);
    stB01(1); stA2(1);
    asm volatile("s_waitcnt vmcnt(6)" ::: "memory");
    BAR;

    for (int t = 0; t < nt; ++t) {
        const char* buf = smem + (t % 3) * 49152;
        const bool st2 = (t + 2 < nt);
        // phA: read A + B(ng=0) | stage (T+2).B
        LDA(buf); LDB(buf, 0);
        if (st2) stB01(t + 2);
        BAR; LGKM; QMM(0); BAR;
        // phB: read B(ng=1) | stage (T+2).A ; tile-boundary vmcnt
        LDB(buf, 1);
        if (st2) stA2(t + 2);
        BAR; LGKM; QMM(1);
        if (t + 1 < nt) {
            if (st2) asm volatile("s_waitcnt vmcnt(6)" ::: "memory");
            else     asm volatile("s_waitcnt vmcnt(0)" ::: "memory");
        }
        BAR;
    }

    // epilogue: per-wave 64x64 via LDS, coalesced stores (post-loop barrier above)
    u16* Es = (u16*)smem + (size_t)wave * 64 * EPAD;
    const int cr = (lane >> 4) << 2;
    const int cc = lane & 15;
#pragma unroll
    for (int n = 0; n < 4; n++) {
        float bv = BIAS ? bias[bn + wn * 64 + n * 16 + cc] : 0.f;
#pragma unroll
        for (int m = 0; m < 4; m++) {
#pragma unroll
            for (int j = 0; j < 4; j++) {
                float v = acc[m][n][j] + bv;
                if (RELU) v = fmaxf(v, 0.f);
                Es[(m * 16 + cr + j) * EPAD + n * 16 + cc] = f2bf(v);
            }
        }
    }
    const int rl = lane >> 3;
    const int c8 = (lane & 7) * 8;
#pragma unroll
    for (int it = 0; it < 8; it++) {
        int lr = it * 8 + rl;
        u16x8 vv = *(const u16x8*)(Es + lr * EPAD + c8);
        int grow = bm + wm * 64 + lr;
        if (grow < M)
            *(u16x8*)(C + (size_t)grow * N + bn + wn * 64 + c8) = vv;
    }
#undef BAR
#undef LGKM
}

// ---------------- 128x128 bf16 MFMA GEMM, BK=64 (L3, N=128) ----------------
#define GBM 128
#define GBN 128
#define GBK 64

template <bool BIAS, bool RELU>
__global__ __launch_bounds__(256) void mfma_gemm(
    const u16* __restrict__ A, const u16* __restrict__ Bt,
    const float* __restrict__ bias, u16* __restrict__ C,
    int M, int N, int K, int nbx) {
    __shared__ __align__(16) char smem[4 * 64 * EPAD * 2];
    u16* As = (u16*)smem;
    u16* Bs = (u16*)(smem + 16384);
    const int tid = threadIdx.x;
    const int lane = tid & 63;
    const int wave = tid >> 6;
    const int wr = wave >> 1, wc = wave & 1;

    const int nwg = gridDim.x;
    int lg;
    { int q = nwg >> 3, r = nwg & 7, xc = blockIdx.x & 7, pos = blockIdx.x >> 3;
      lg = (xc < r ? xc * (q + 1) : r * (q + 1) + (xc - r) * q) + pos; }
    const int bm = (lg / nbx) * GBM;
    const int bn = (lg % nbx) * GBN;

    f32x4 acc[4][4];
#pragma unroll
    for (int m = 0; m < 4; m++)
#pragma unroll
        for (int n = 0; n < 4; n++) acc[m][n] = (f32x4)0.f;

    const int rbase = tid >> 3;
    const int csw = (((tid & 7) ^ (rbase & 7)) << 4);
    const size_t sK = (size_t)K * 2;
    const char* Ab = (const char*)A;
    const char* Bb = (const char*)Bt;
    size_t ga[4], gb[4];
#pragma unroll
    for (int i = 0; i < 4; i++) {
        int r0 = rbase + 32 * i;
        int ar = bm + r0; if (ar >= M) ar = M - 1;
        int br = bn + r0; if (br >= N) br = N - 1;
        ga[i] = (size_t)ar * sK + csw;
        gb[i] = (size_t)br * sK + csw;
    }
    const int od = tid * 16;

    const int fr = lane & 15, g = lane >> 4;
    int aoff[2][4], boff[2][4];
#pragma unroll
    for (int ks = 0; ks < 2; ks++) {
        const int sw = (((ks << 2) + g) ^ (fr & 7)) << 4;
#pragma unroll
        for (int m = 0; m < 4; m++) {
            aoff[ks][m] = (wr * 64 + m * 16 + fr) * 128 + sw;
            boff[ks][m] = (wc * 64 + m * 16 + fr) * 128 + sw;
        }
    }

    for (int k0 = 0; k0 < K; k0 += GBK) {
        const size_t kb = (size_t)k0 * 2;
#pragma unroll
        for (int i = 0; i < 4; i++) {
            __builtin_amdgcn_global_load_lds(GLB_AS(Ab + ga[i] + kb), LDS_AS((char*)As + od + i * 4096), 16, 0, 0);
            __builtin_amdgcn_global_load_lds(GLB_AS(Bb + gb[i] + kb), LDS_AS((char*)Bs + od + i * 4096), 16, 0, 0);
        }
        __syncthreads();
#pragma unroll
        for (int ks = 0; ks < 2; ks++) {
            bf16x8 af[4], bfr[4];
#pragma unroll
            for (int n = 0; n < 4; n++) bfr[n] = *(const bf16x8*)((char*)Bs + boff[ks][n]);
#pragma unroll
            for (int m = 0; m < 4; m++) af[m] = *(const bf16x8*)((char*)As + aoff[ks][m]);
#pragma unroll
            for (int m = 0; m < 4; m++)
#pragma unroll
                for (int n = 0; n < 4; n++)
                    acc[m][n] = __builtin_amdgcn_mfma_f32_16x16x32_bf16(af[m], bfr[n], acc[m][n], 0, 0, 0);
        }
        __syncthreads();
    }

    u16* Es = (u16*)smem + (size_t)wave * 64 * EPAD;
    const int cr = (lane >> 4) << 2;
    const int cc = lane & 15;
#pragma unroll
    for (int n = 0; n < 4; n++) {
        float bv = BIAS ? bias[bn + wc * 64 + n * 16 + cc] : 0.f;
#pragma unroll
        for (int m = 0; m < 4; m++) {
#pragma unroll
            for (int j = 0; j < 4; j++) {
                float v = acc[m][n][j] + bv;
                if (RELU) v = fmaxf(v, 0.f);
                Es[(m * 16 + cr + j) * EPAD + n * 16 + cc] = f2bf(v);
            }
        }
    }
    const int rl = lane >> 3;
    const int c8 = (lane & 7) * 8;
#pragma unroll
    for (int it = 0; it < 8; it++) {
        int lr = it * 8 + rl;
        u16x8 vv = *(const u16x8*)(Es + lr * EPAD + c8);
        int grow = bm + wr * 64 + lr;
        if (grow < M)
            *(u16x8*)(C + (size_t)grow * N + bn + wc * 64 + c8) = vv;
    }
}

// ---------------- launch ----------------
extern "C" void kernel_launch(void* const* d_in, const int* in_sizes, int n_in,
                              void* d_out, int out_size, void* d_ws, size_t ws_size,
                              hipStream_t stream) {
    const float* x   = (const float*)d_in[0];
    const void*  ei  = d_in[1];
    const float* W1  = (const float*)d_in[2];
    const float* b1  = (const float*)d_in[3];
    const float* W2  = (const float*)d_in[4];
    const float* b2  = (const float*)d_in[5];
    const float* W3  = (const float*)d_in[6];
    const float* b3  = (const float*)d_in[7];
    const float* Wfc = (const float*)d_in[8];
    const float* bfc = (const float*)d_in[9];
    float* out = (float*)d_out;

    char* ws = (char*)d_ws;
    size_t off = 0;
    auto take = [&](size_t bytes) -> void* {
        off = (off + 255) & ~(size_t)255;
        void* p = ws + off;
        off += bytes;
        return p;
    };
    int*   deg     = (int*)take((size_t)NN * 4);
    int*   row_off = (int*)take((size_t)(NN + 1) * 4);
    int*   cursor  = (int*)take((size_t)NN * 4);
    float* isq     = (float*)take((size_t)NN * 4);
    float* idg     = (float*)take((size_t)NN * 4);
    int*   ssrc    = (int*)take((size_t)NE * 4);
    float* snorm   = (float*)take((size_t)NE * 4);
    int*   flag    = (int*)take(256);
    int*   bsum    = (int*)take((size_t)(NBLK + 1) * 4);
    u16*   Wt1     = (u16*)take((size_t)1024 * 128 * 2);
    u16*   Wt2     = (u16*)take((size_t)512 * 1024 * 2);
    u16*   Wt3     = (u16*)take((size_t)128 * 512 * 2);
    u16*   xbf     = (u16*)take((size_t)NN * 128 * 2);   // bf16 x
    u16*   rA      = (u16*)take((size_t)NN * 128 * 2);   // a0, later g3
    u16*   rH      = (u16*)take((size_t)NN * 1024 * 2);  // h1, later h2
    u16*   rT      = (u16*)take((size_t)NN * 512 * 2);   // t2

    // zero deg + flag via async memset (graph-capturable)
    hipMemsetAsync(deg, 0, (size_t)NN * 4, stream);
    hipMemsetAsync(flag, 0, 4, stream);

    // merged prep (weights + x conversion) — independent of graph setup
    k_prep<<<PREP_BLOCKS, 256, 0, stream>>>(W1, Wt1, W2, Wt2, W3, Wt3, x, xbf);

    // graph setup
    k_detect<<<(NE + 255) / 256, 256, 0, stream>>>(ei, flag);
    k_hist<<<(NE + 255) / 256, 256, 0, stream>>>(ei, flag, deg);
    k_scan1<<<NBLK, SB, 0, stream>>>(deg, row_off, bsum, isq, idg);
    k_scan2<<<1, SB, 0, stream>>>(bsum);
    k_scan3<<<NBLK, SB, 0, stream>>>(row_off, cursor, bsum);
    k_scatter<<<(NE + 255) / 256, 256, 0, stream>>>(ei, flag, isq, cursor, ssrc, snorm);

    const int MB256 = (NN + 255) / 256;  // 196
    const int MB128 = (NN + 127) / 128;  // 391

    // L1: aggregate bf16 x, 8-phase GEMM(+b1,relu) -> h1 (784 blocks = 3.06 rounds)
    u16* a0 = rA;
    k_agg<128, 1, false, false><<<NN, 64, 0, stream>>>(xbf, a0, row_off, ssrc, snorm, idg, nullptr);
    u16* h1 = rH;
    gemm8<true, true><<<MB256 * 4, 512, 0, stream>>>(a0, Wt1, b1, h1, NN, 1024, 128, 4);

    // L2: 128x256 3-ring GEMM -> t2 (782 blocks = 3.05 rounds), aggregate(+b2,relu) -> h2
    u16* t2 = rT;
    gemm8h<false, false><<<MB128 * 2, 512, 0, stream>>>(h1, Wt2, nullptr, t2, NN, 512, 1024, 2);
    u16* h2 = rH;  // h1 dead
    k_agg<512, 1, true, true><<<NN, 64, 0, stream>>>(t2, h2, row_off, ssrc, snorm, idg, b2);

    // L3: GEMM -> g3, then fused aggregate(+b3,relu)+FC -> out
    u16* g3 = rA;  // a0 dead
    mfma_gemm<false, false><<<MB128, 256, 0, stream>>>(h2, Wt3, nullptr, g3, NN, 128, 512, 1);
    k_agg_fc<<<NN, 64, 0, stream>>>(g3, out, row_off, ssrc, snorm, idg, b3, Wfc, bfc);

    (void)in_sizes; (void)n_in; (void)out_size; (void)ws_size;
}

// Round 15
// 422.103 us; speedup vs baseline: 1.0381x; 1.0381x over previous
//
#include <hip/hip_runtime.h>
#include <hip/hip_bf16.h>
#include <cstdint>
#include <cstddef>

#define NN 50000
#define NE 400000
typedef long long i64;
typedef unsigned short u16;
typedef __attribute__((ext_vector_type(8))) short bf16x8;
typedef __attribute__((ext_vector_type(8))) unsigned short u16x8;
typedef __attribute__((ext_vector_type(4))) unsigned short u16x4;
typedef __attribute__((ext_vector_type(4))) float f32x4;

__device__ inline u16 f2bf(float f) {  // RNE
    unsigned u = __float_as_uint(f);
    u += 0x7fffu + ((u >> 16) & 1u);
    return (u16)(u >> 16);
}
__device__ inline float bf2f(u16 b) { return __uint_as_float(((unsigned)b) << 16); }

// ---------------- setup kernels ----------------
__global__ void k_detect(const void* __restrict__ ei, int* __restrict__ flag) {
    int i = blockIdx.x * blockDim.x + threadIdx.x;
    if (i < NE) {
        i64 v = ((const i64*)ei)[i];
        if (v < 0 || v >= NN) atomicOr(flag, 1);
    }
}

__device__ inline int edge_at(const void* ei, int f32idx, int half, int i) {
    if (f32idx) return ((const int*)ei)[half * NE + i];
    return (int)((const i64*)ei)[half * NE + i];
}

__global__ void k_hist(const void* __restrict__ ei, const int* __restrict__ flag,
                       int* __restrict__ deg) {
    int i = blockIdx.x * blockDim.x + threadIdx.x;
    if (i < NE) {
        int d = edge_at(ei, *flag, 1, i);
        if ((unsigned)d < NN) atomicAdd(&deg[d], 1);
    }
}

// ---------------- 3-phase parallel scan (scan1 also does node_setup) ----------------
#define SB 256
#define NBLK ((NN + SB - 1) / SB)  // 196

__global__ __launch_bounds__(SB) void k_scan1(const int* __restrict__ deg,
                                              int* __restrict__ excl,
                                              int* __restrict__ bsum,
                                              float* __restrict__ inv_sqrt,
                                              float* __restrict__ inv_deg) {
    __shared__ int s[SB];
    int t = threadIdx.x;
    int i = blockIdx.x * SB + t;
    int v = (i < NN) ? deg[i] : 0;
    if (i < NN) {
        float d = (float)v + 1.0f;
        inv_sqrt[i] = rsqrtf(d);
        inv_deg[i]  = 1.0f / d;
    }
    s[t] = v;
    __syncthreads();
    for (int off = 1; off < SB; off <<= 1) {
        int x = (t >= off) ? s[t - off] : 0;
        __syncthreads();
        s[t] += x;
        __syncthreads();
    }
    if (i < NN) excl[i] = s[t] - v;
    if (t == SB - 1) bsum[blockIdx.x] = s[t];
}

__global__ __launch_bounds__(SB) void k_scan2(int* __restrict__ bsum) {
    __shared__ int s[SB];
    int t = threadIdx.x;
    int v = (t < NBLK) ? bsum[t] : 0;
    s[t] = v;
    __syncthreads();
    for (int off = 1; off < SB; off <<= 1) {
        int x = (t >= off) ? s[t - off] : 0;
        __syncthreads();
        s[t] += x;
        __syncthreads();
    }
    if (t < NBLK) bsum[t] = s[t] - v;
    if (t == NBLK - 1) bsum[NBLK] = s[t];
}

__global__ __launch_bounds__(SB) void k_scan3(int* __restrict__ row_off,
                                              int* __restrict__ cursor,
                                              const int* __restrict__ bsum) {
    int i = blockIdx.x * SB + threadIdx.x;
    if (i < NN) {
        int r = row_off[i] + bsum[blockIdx.x];
        row_off[i] = r;
        cursor[i]  = r;
    }
    if (i == 0) row_off[NN] = bsum[NBLK];
}

__global__ void k_scatter(const void* __restrict__ ei, const int* __restrict__ flag,
                          const float* __restrict__ inv_sqrt,
                          int* __restrict__ cursor, int* __restrict__ ssrc,
                          float* __restrict__ snorm) {
    int i = blockIdx.x * blockDim.x + threadIdx.x;
    if (i < NE) {
        int f = *flag;
        int s = edge_at(ei, f, 0, i);
        int d = edge_at(ei, f, 1, i);
        if ((unsigned)s < NN && (unsigned)d < NN) {
            int pos = atomicAdd(&cursor[d], 1);
            if ((unsigned)pos < NE) {
                ssrc[pos]  = s;
                snorm[pos] = inv_sqrt[s] * inv_sqrt[d];
            }
        }
    }
}

// ---------------- merged prep: 3x weight transpose (f32->bf16, coalesced) + x->bf16 ----------------
#define PREP_BLOCKS 6954
__global__ __launch_bounds__(256) void k_prep(const float* __restrict__ W1, u16* __restrict__ Wt1,
                                              const float* __restrict__ W2, u16* __restrict__ Wt2,
                                              const float* __restrict__ W3, u16* __restrict__ Wt3,
                                              const float* __restrict__ x, u16* __restrict__ xb) {
    __shared__ u16 tile[32][33];
    int b = blockIdx.x;
    if (b < 704) {
        const float* W; u16* Wt; int K, N, base;
        if (b < 128)      { W = W1; Wt = Wt1; K = 128;  N = 1024; base = 0; }
        else if (b < 640) { W = W2; Wt = Wt2; K = 1024; N = 512;  base = 128; }
        else              { W = W3; Wt = Wt3; K = 512;  N = 128;  base = 640; }
        int bb = b - base;
        int ntk = K >> 5;
        int tk = bb % ntk, tn = bb / ntk;
        int lx = threadIdx.x & 31, ly = threadIdx.x >> 5;
#pragma unroll
        for (int r = 0; r < 32; r += 8)
            tile[ly + r][lx] = f2bf(W[(size_t)(tk * 32 + ly + r) * N + tn * 32 + lx]);
        __syncthreads();
#pragma unroll
        for (int r = 0; r < 32; r += 8)
            Wt[(size_t)(tn * 32 + ly + r) * K + tk * 32 + lx] = tile[lx][ly + r];
    } else {
        int i = (b - 704) * 256 + threadIdx.x;
        if (i < NN * 128 / 4) {
            float4 v = ((const float4*)x)[i];
            u16x4 r;
            r[0] = f2bf(v.x); r[1] = f2bf(v.y); r[2] = f2bf(v.z); r[3] = f2bf(v.w);
            ((u16x4*)xb)[i] = r;
        }
    }
}

// ---------------- CSR aggregation (bf16 in), 4-way edge-unrolled ----------------
template <int W, int TOUT, bool BIAS, bool RELU>
__global__ __launch_bounds__(64) void k_agg(const u16* __restrict__ X, void* __restrict__ Yv,
                      const int* __restrict__ row_off, const int* __restrict__ ssrc,
                      const float* __restrict__ snorm, const float* __restrict__ inv_deg,
                      const float* __restrict__ bias) {
    constexpr int E = W / 64;
    int node = blockIdx.x;
    int lane = threadIdx.x;
    int col = lane * E;
    int beg = row_off[node], end = row_off[node + 1];
    float acc[E];
#pragma unroll
    for (int v = 0; v < E; v++) acc[v] = 0.f;

    auto rowp = [&](int srow) -> const u16* {
        unsigned s = (unsigned)srow;
        if (s >= NN) s = 0;
        return X + (size_t)s * W + col;
    };
    auto fma8 = [&](u16x8 t, float w) {
#pragma unroll
        for (int j = 0; j < 8; j++) acc[j] = fmaf(bf2f(t[j]), w, acc[j]);
    };
    auto fma2 = [&](unsigned t, float w) {
        acc[0] = fmaf(bf2f((u16)(t & 0xffff)), w, acc[0]);
        acc[1] = fmaf(bf2f((u16)(t >> 16)), w, acc[1]);
    };

    int e = beg;
    for (; e + 3 < end; e += 4) {
        int s0 = ssrc[e], s1 = ssrc[e + 1], s2 = ssrc[e + 2], s3 = ssrc[e + 3];
        float w0 = snorm[e], w1 = snorm[e + 1], w2 = snorm[e + 2], w3 = snorm[e + 3];
        w0 = ((unsigned)s0 < NN) ? w0 : 0.f;
        w1 = ((unsigned)s1 < NN) ? w1 : 0.f;
        w2 = ((unsigned)s2 < NN) ? w2 : 0.f;
        w3 = ((unsigned)s3 < NN) ? w3 : 0.f;
        if constexpr (E == 2) {
            unsigned t0 = *(const unsigned*)rowp(s0);
            unsigned t1 = *(const unsigned*)rowp(s1);
            unsigned t2 = *(const unsigned*)rowp(s2);
            unsigned t3 = *(const unsigned*)rowp(s3);
            fma2(t0, w0); fma2(t1, w1); fma2(t2, w2); fma2(t3, w3);
        } else {
            u16x8 t0 = *(const u16x8*)rowp(s0);
            u16x8 t1 = *(const u16x8*)rowp(s1);
            u16x8 t2 = *(const u16x8*)rowp(s2);
            u16x8 t3 = *(const u16x8*)rowp(s3);
            fma8(t0, w0); fma8(t1, w1); fma8(t2, w2); fma8(t3, w3);
        }
    }
    for (; e < end; e++) {
        int s = ssrc[e];
        if ((unsigned)s >= NN) continue;
        float w = snorm[e];
        if constexpr (E == 2) fma2(*(const unsigned*)rowp(s), w);
        else                  fma8(*(const u16x8*)rowp(s), w);
    }
    {   // self-loop
        float w = inv_deg[node];
        if constexpr (E == 2) fma2(*(const unsigned*)(X + (size_t)node * W + col), w);
        else                  fma8(*(const u16x8*)(X + (size_t)node * W + col), w);
    }

#pragma unroll
    for (int v = 0; v < E; v++) {
        float val = acc[v];
        if (BIAS) val += bias[col + v];
        if (RELU) val = fmaxf(val, 0.f);
        if constexpr (TOUT == 0) ((float*)Yv)[(size_t)node * W + col + v] = val;
        else ((u16*)Yv)[(size_t)node * W + col + v] = f2bf(val);
    }
}

// ---------------- final aggregation + fused FC (4-way unrolled) ----------------
__global__ __launch_bounds__(64) void k_agg_fc(const u16* __restrict__ X,
                      float* __restrict__ out,
                      const int* __restrict__ row_off, const int* __restrict__ ssrc,
                      const float* __restrict__ snorm, const float* __restrict__ inv_deg,
                      const float* __restrict__ b3, const float* __restrict__ Wfc,
                      const float* __restrict__ bfc) {
    __shared__ float hrow[128];
    int node = blockIdx.x;
    int lane = threadIdx.x;
    int col = lane * 2;
    int beg = row_off[node], end = row_off[node + 1];
    float a0 = 0.f, a1 = 0.f;

    auto rowu = [&](int srow) -> unsigned {
        unsigned s = (unsigned)srow;
        if (s >= NN) s = 0;
        return *(const unsigned*)(X + (size_t)s * 128 + col);
    };
    int e = beg;
    for (; e + 3 < end; e += 4) {
        int s0 = ssrc[e], s1 = ssrc[e + 1], s2 = ssrc[e + 2], s3 = ssrc[e + 3];
        float w0 = snorm[e], w1 = snorm[e + 1], w2 = snorm[e + 2], w3 = snorm[e + 3];
        w0 = ((unsigned)s0 < NN) ? w0 : 0.f;
        w1 = ((unsigned)s1 < NN) ? w1 : 0.f;
        w2 = ((unsigned)s2 < NN) ? w2 : 0.f;
        w3 = ((unsigned)s3 < NN) ? w3 : 0.f;
        unsigned t0 = rowu(s0), t1 = rowu(s1), t2 = rowu(s2), t3 = rowu(s3);
        a0 = fmaf(bf2f((u16)(t0 & 0xffff)), w0, a0); a1 = fmaf(bf2f((u16)(t0 >> 16)), w0, a1);
        a0 = fmaf(bf2f((u16)(t1 & 0xffff)), w1, a0); a1 = fmaf(bf2f((u16)(t1 >> 16)), w1, a1);
        a0 = fmaf(bf2f((u16)(t2 & 0xffff)), w2, a0); a1 = fmaf(bf2f((u16)(t2 >> 16)), w2, a1);
        a0 = fmaf(bf2f((u16)(t3 & 0xffff)), w3, a0); a1 = fmaf(bf2f((u16)(t3 >> 16)), w3, a1);
    }
    for (; e < end; e++) {
        int s = ssrc[e];
        if ((unsigned)s >= NN) continue;
        float w = snorm[e];
        unsigned t = *(const unsigned*)(X + (size_t)s * 128 + col);
        a0 = fmaf(bf2f((u16)(t & 0xffff)), w, a0);
        a1 = fmaf(bf2f((u16)(t >> 16)), w, a1);
    }
    {
        float w = inv_deg[node];
        unsigned t = *(const unsigned*)(X + (size_t)node * 128 + col);
        a0 = fmaf(bf2f((u16)(t & 0xffff)), w, a0);
        a1 = fmaf(bf2f((u16)(t >> 16)), w, a1);
    }
    hrow[col]     = fmaxf(a0 + b3[col], 0.f);
    hrow[col + 1] = fmaxf(a1 + b3[col + 1], 0.f);
    __syncthreads();
    if (lane < 40) {
        float s = bfc[lane];
#pragma unroll 8
        for (int k = 0; k < 128; k++)
            s = fmaf(hrow[k], Wfc[k * 40 + lane], s);
        out[(size_t)node * 40 + lane] = s;
    }
}

#define LDS_AS(p) ((__attribute__((address_space(3))) void*)(p))
#define GLB_AS(p) ((const __attribute__((address_space(1))) void*)(p))
#define EPAD 68

// ---------------- 8-phase 256x256 bf16 MFMA GEMM (L1, L2) ----------------
template <bool BIAS, bool RELU>
__global__ __launch_bounds__(512, 2) void gemm8(
    const u16* __restrict__ A, const u16* __restrict__ Bt,
    const float* __restrict__ bias, u16* __restrict__ C,
    int M, int N, int K, int nbx) {
    __shared__ __align__(16) char smem[131072];
    char* buf0 = smem;
    char* buf1 = smem + 65536;
    const int tid = threadIdx.x;
    const int lane = tid & 63;
    const int wave = tid >> 6;
    const int wm = wave >> 2;  // 0..1
    const int wn = wave & 3;   // 0..3

    const int nwg = gridDim.x;
    int lg;
    { int q = nwg >> 3, r = nwg & 7, xc = blockIdx.x & 7, pos = blockIdx.x >> 3;
      lg = (xc < r ? xc * (q + 1) : r * (q + 1) + (xc - r) * q) + pos; }
    const int bm = (lg / nbx) * 256;
    const int bn = (lg % nbx) * 256;

    f32x4 acc[8][4];
#pragma unroll
    for (int m = 0; m < 8; m++)
#pragma unroll
        for (int n = 0; n < 4; n++) acc[m][n] = (f32x4)0.f;

    const int rb = tid >> 3;
    const int csw = ((tid & 7) ^ (rb & 7)) << 4;
    const int dstA = rb * 128 + (tid & 7) * 16;
    const size_t sK = (size_t)K * 2;
    const char* Ab = (const char*)A;
    const char* Bb = (const char*)Bt;
    size_t ga[2][2], gb[2][2];
#pragma unroll
    for (int h = 0; h < 2; h++)
#pragma unroll
        for (int j = 0; j < 2; j++) {
            int ar = bm + h * 128 + j * 64 + rb; if (ar >= M) ar = M - 1;
            int br = bn + h * 128 + j * 64 + rb;
            ga[h][j] = (size_t)ar * sK + csw;
            gb[h][j] = (size_t)br * sK + csw;
        }

    auto stA = [&](char* buf, size_t kb, int h) {
        __builtin_amdgcn_global_load_lds(GLB_AS(Ab + ga[h][0] + kb), LDS_AS(buf + h * 16384 + dstA), 16, 0, 0);
        __builtin_amdgcn_global_load_lds(GLB_AS(Ab + ga[h][1] + kb), LDS_AS(buf + h * 16384 + 8192 + dstA), 16, 0, 0);
    };
    auto stB = [&](char* buf, size_t kb, int h) {
        __builtin_amdgcn_global_load_lds(GLB_AS(Bb + gb[h][0] + kb), LDS_AS(buf + 32768 + h * 16384 + dstA), 16, 0, 0);
        __builtin_amdgcn_global_load_lds(GLB_AS(Bb + gb[h][1] + kb), LDS_AS(buf + 32768 + h * 16384 + 8192 + dstA), 16, 0, 0);
    };

    const int fr = lane & 15, g = lane >> 4;
    const int ksw0 = (((0 << 2) + g) ^ (fr & 7)) << 4;
    const int ksw1 = (((1 << 2) + g) ^ (fr & 7)) << 4;
    const int aRow = (wm * 128 + fr) * 128;
    const int bRow = 32768 + (wn * 64 + fr) * 128;

    bf16x8 af[4][2], bf[4][2];
    auto LDA = [&](const char* buf, int mg) {
#pragma unroll
        for (int m = 0; m < 4; m++) {
            af[m][0] = *(const bf16x8*)(buf + aRow + mg * 8192 + m * 2048 + ksw0);
            af[m][1] = *(const bf16x8*)(buf + aRow + mg * 8192 + m * 2048 + ksw1);
        }
    };
    auto LDB = [&](const char* buf, int ng) {
#pragma unroll
        for (int n = 0; n < 2; n++) {
            bf[ng * 2 + n][0] = *(const bf16x8*)(buf + bRow + (ng * 2 + n) * 2048 + ksw0);
            bf[ng * 2 + n][1] = *(const bf16x8*)(buf + bRow + (ng * 2 + n) * 2048 + ksw1);
        }
    };
    auto QMM = [&](int mg, int ng) {
        __builtin_amdgcn_s_setprio(1);
#pragma unroll
        for (int ks = 0; ks < 2; ks++)
#pragma unroll
            for (int m = 0; m < 4; m++)
#pragma unroll
                for (int n = 0; n < 2; n++)
                    acc[mg * 4 + m][ng * 2 + n] = __builtin_amdgcn_mfma_f32_16x16x32_bf16(
                        af[m][ks], bf[ng * 2 + n][ks], acc[mg * 4 + m][ng * 2 + n], 0, 0, 0);
        __builtin_amdgcn_s_setprio(0);
    };

#define BAR  __builtin_amdgcn_s_barrier()
#define LGKM do { asm volatile("s_waitcnt lgkmcnt(0)" ::: "memory"); __builtin_amdgcn_sched_barrier(0); } while (0)

    const int nit = K >> 7;

    stB(buf0, 0, 0); stB(buf0, 0, 1);
    stA(buf0, 0, 0); stA(buf0, 0, 1);
    stB(buf1, 128, 0); stB(buf1, 128, 1);
    asm volatile("s_waitcnt vmcnt(4)" ::: "memory");
    BAR;

    for (int it2 = 0; it2 < nit; ++it2) {
        const bool lastit = (it2 == nit - 1);
        const size_t kb = (size_t)it2 * 256;
        LDA(buf0, 0); LDB(buf0, 0);
        stA(buf1, kb + 128, 0);
        BAR; LGKM; QMM(0, 0); BAR;
        LDB(buf0, 1);
        stA(buf1, kb + 128, 1);
        BAR; LGKM; QMM(0, 1); BAR;
        LDA(buf0, 1);
        if (!lastit) stB(buf0, kb + 256, 0);
        BAR; LGKM; QMM(1, 0); BAR;
        if (!lastit) stB(buf0, kb + 256, 1);
        BAR; QMM(1, 1);
        if (lastit) asm volatile("s_waitcnt vmcnt(0)" ::: "memory");
        else        asm volatile("s_waitcnt vmcnt(4)" ::: "memory");
        BAR;
        LDA(buf1, 0); LDB(buf1, 0);
        if (!lastit) stA(buf0, kb + 256, 0);
        BAR; LGKM; QMM(0, 0); BAR;
        LDB(buf1, 1);
        if (!lastit) stA(buf0, kb + 256, 1);
        BAR; LGKM; QMM(0, 1); BAR;
        LDA(buf1, 1);
        if (!lastit) stB(buf1, kb + 384, 0);
        BAR; LGKM; QMM(1, 0); BAR;
        if (!lastit) stB(buf1, kb + 384, 1);
        BAR; QMM(1, 1);
        if (!lastit) asm volatile("s_waitcnt vmcnt(4)" ::: "memory");
        BAR;
    }

    u16* Es = (u16*)(smem + (size_t)wave * (64 * EPAD * 2));
    const int cr = (lane >> 4) << 2;
    const int cc = lane & 15;
    const int rl = lane >> 3;
    const int c8 = (lane & 7) * 8;
#pragma unroll
    for (int pass = 0; pass < 2; pass++) {
#pragma unroll
        for (int n = 0; n < 4; n++) {
            float bv = BIAS ? bias[bn + wn * 64 + n * 16 + cc] : 0.f;
#pragma unroll
            for (int m = 0; m < 4; m++) {
#pragma unroll
                for (int j = 0; j < 4; j++) {
                    float v = acc[pass * 4 + m][n][j] + bv;
                    if (RELU) v = fmaxf(v, 0.f);
                    Es[(m * 16 + cr + j) * EPAD + n * 16 + cc] = f2bf(v);
                }
            }
        }
#pragma unroll
        for (int itr = 0; itr < 8; itr++) {
            int lr = itr * 8 + rl;
            u16x8 vv = *(const u16x8*)(Es + lr * EPAD + c8);
            int grow = bm + wm * 128 + pass * 64 + lr;
            if (grow < M)
                *(u16x8*)(C + (size_t)grow * N + bn + wn * 64 + c8) = vv;
        }
    }
#undef BAR
#undef LGKM
}

// ---------------- 128x128 bf16 MFMA GEMM, BK=64 (L3, N=128) ----------------
#define GBM 128
#define GBN 128
#define GBK 64

template <bool BIAS, bool RELU>
__global__ __launch_bounds__(256) void mfma_gemm(
    const u16* __restrict__ A, const u16* __restrict__ Bt,
    const float* __restrict__ bias, u16* __restrict__ C,
    int M, int N, int K, int nbx) {
    __shared__ __align__(16) char smem[4 * 64 * EPAD * 2];
    u16* As = (u16*)smem;
    u16* Bs = (u16*)(smem + 16384);
    const int tid = threadIdx.x;
    const int lane = tid & 63;
    const int wave = tid >> 6;
    const int wr = wave >> 1, wc = wave & 1;

    const int nwg = gridDim.x;
    int lg;
    { int q = nwg >> 3, r = nwg & 7, xc = blockIdx.x & 7, pos = blockIdx.x >> 3;
      lg = (xc < r ? xc * (q + 1) : r * (q + 1) + (xc - r) * q) + pos; }
    const int bm = (lg / nbx) * GBM;
    const int bn = (lg % nbx) * GBN;

    f32x4 acc[4][4];
#pragma unroll
    for (int m = 0; m < 4; m++)
#pragma unroll
        for (int n = 0; n < 4; n++) acc[m][n] = (f32x4)0.f;

    const int rbase = tid >> 3;
    const int csw = (((tid & 7) ^ (rbase & 7)) << 4);
    const size_t sK = (size_t)K * 2;
    const char* Ab = (const char*)A;
    const char* Bb = (const char*)Bt;
    size_t ga[4], gb[4];
#pragma unroll
    for (int i = 0; i < 4; i++) {
        int r0 = rbase + 32 * i;
        int ar = bm + r0; if (ar >= M) ar = M - 1;
        int br = bn + r0; if (br >= N) br = N - 1;
        ga[i] = (size_t)ar * sK + csw;
        gb[i] = (size_t)br * sK + csw;
    }
    const int od = tid * 16;

    const int fr = lane & 15, g = lane >> 4;
    int aoff[2][4], boff[2][4];
#pragma unroll
    for (int ks = 0; ks < 2; ks++) {
        const int sw = (((ks << 2) + g) ^ (fr & 7)) << 4;
#pragma unroll
        for (int m = 0; m < 4; m++) {
            aoff[ks][m] = (wr * 64 + m * 16 + fr) * 128 + sw;
            boff[ks][m] = (wc * 64 + m * 16 + fr) * 128 + sw;
        }
    }

    for (int k0 = 0; k0 < K; k0 += GBK) {
        const size_t kb = (size_t)k0 * 2;
#pragma unroll
        for (int i = 0; i < 4; i++) {
            __builtin_amdgcn_global_load_lds(GLB_AS(Ab + ga[i] + kb), LDS_AS((char*)As + od + i * 4096), 16, 0, 0);
            __builtin_amdgcn_global_load_lds(GLB_AS(Bb + gb[i] + kb), LDS_AS((char*)Bs + od + i * 4096), 16, 0, 0);
        }
        __syncthreads();
#pragma unroll
        for (int ks = 0; ks < 2; ks++) {
            bf16x8 af[4], bfr[4];
#pragma unroll
            for (int n = 0; n < 4; n++) bfr[n] = *(const bf16x8*)((char*)Bs + boff[ks][n]);
#pragma unroll
            for (int m = 0; m < 4; m++) af[m] = *(const bf16x8*)((char*)As + aoff[ks][m]);
#pragma unroll
            for (int m = 0; m < 4; m++)
#pragma unroll
                for (int n = 0; n < 4; n++)
                    acc[m][n] = __builtin_amdgcn_mfma_f32_16x16x32_bf16(af[m], bfr[n], acc[m][n], 0, 0, 0);
        }
        __syncthreads();
    }

    u16* Es = (u16*)smem + (size_t)wave * 64 * EPAD;
    const int cr = (lane >> 4) << 2;
    const int cc = lane & 15;
#pragma unroll
    for (int n = 0; n < 4; n++) {
        float bv = BIAS ? bias[bn + wc * 64 + n * 16 + cc] : 0.f;
#pragma unroll
        for (int m = 0; m < 4; m++) {
#pragma unroll
            for (int j = 0; j < 4; j++) {
                float v = acc[m][n][j] + bv;
                if (RELU) v = fmaxf(v, 0.f);
                Es[(m * 16 + cr + j) * EPAD + n * 16 + cc] = f2bf(v);
            }
        }
    }
    const int rl = lane >> 3;
    const int c8 = (lane & 7) * 8;
#pragma unroll
    for (int it = 0; it < 8; it++) {
        int lr = it * 8 + rl;
        u16x8 vv = *(const u16x8*)(Es + lr * EPAD + c8);
        int grow = bm + wr * 64 + lr;
        if (grow < M)
            *(u16x8*)(C + (size_t)grow * N + bn + wc * 64 + c8) = vv;
    }
}

// ---------------- launch ----------------
extern "C" void kernel_launch(void* const* d_in, const int* in_sizes, int n_in,
                              void* d_out, int out_size, void* d_ws, size_t ws_size,
                              hipStream_t stream) {
    const float* x   = (const float*)d_in[0];
    const void*  ei  = d_in[1];
    const float* W1  = (const float*)d_in[2];
    const float* b1  = (const float*)d_in[3];
    const float* W2  = (const float*)d_in[4];
    const float* b2  = (const float*)d_in[5];
    const float* W3  = (const float*)d_in[6];
    const float* b3  = (const float*)d_in[7];
    const float* Wfc = (const float*)d_in[8];
    const float* bfc = (const float*)d_in[9];
    float* out = (float*)d_out;

    char* ws = (char*)d_ws;
    size_t off = 0;
    auto take = [&](size_t bytes) -> void* {
        off = (off + 255) & ~(size_t)255;
        void* p = ws + off;
        off += bytes;
        return p;
    };
    int*   deg     = (int*)take((size_t)NN * 4);
    int*   row_off = (int*)take((size_t)(NN + 1) * 4);
    int*   cursor  = (int*)take((size_t)NN * 4);
    float* isq     = (float*)take((size_t)NN * 4);
    float* idg     = (float*)take((size_t)NN * 4);
    int*   ssrc    = (int*)take((size_t)NE * 4);
    float* snorm   = (float*)take((size_t)NE * 4);
    int*   flag    = (int*)take(256);
    int*   bsum    = (int*)take((size_t)(NBLK + 1) * 4);
    u16*   Wt1     = (u16*)take((size_t)1024 * 128 * 2);
    u16*   Wt2     = (u16*)take((size_t)512 * 1024 * 2);
    u16*   Wt3     = (u16*)take((size_t)128 * 512 * 2);
    u16*   xbf     = (u16*)take((size_t)NN * 128 * 2);   // bf16 x
    u16*   rA      = (u16*)take((size_t)NN * 128 * 2);   // a0, later g3
    u16*   rH      = (u16*)take((size_t)NN * 1024 * 2);  // h1, later h2
    u16*   rT      = (u16*)take((size_t)NN * 512 * 2);   // t2

    // zero deg + flag via async memset (graph-capturable)
    hipMemsetAsync(deg, 0, (size_t)NN * 4, stream);
    hipMemsetAsync(flag, 0, 4, stream);

    // merged prep (weights + x conversion) — independent of graph setup
    k_prep<<<PREP_BLOCKS, 256, 0, stream>>>(W1, Wt1, W2, Wt2, W3, Wt3, x, xbf);

    // graph setup
    k_detect<<<(NE + 255) / 256, 256, 0, stream>>>(ei, flag);
    k_hist<<<(NE + 255) / 256, 256, 0, stream>>>(ei, flag, deg);
    k_scan1<<<NBLK, SB, 0, stream>>>(deg, row_off, bsum, isq, idg);
    k_scan2<<<1, SB, 0, stream>>>(bsum);
    k_scan3<<<NBLK, SB, 0, stream>>>(row_off, cursor, bsum);
    k_scatter<<<(NE + 255) / 256, 256, 0, stream>>>(ei, flag, isq, cursor, ssrc, snorm);

    const int MB256 = (NN + 255) / 256;  // 196
    const int MB128 = (NN + 127) / 128;  // 391

    // L1: aggregate bf16 x, 8-phase GEMM(+b1,relu) -> h1
    u16* a0 = rA;
    k_agg<128, 1, false, false><<<NN, 64, 0, stream>>>(xbf, a0, row_off, ssrc, snorm, idg, nullptr);
    u16* h1 = rH;
    gemm8<true, true><<<MB256 * 4, 512, 0, stream>>>(a0, Wt1, b1, h1, NN, 1024, 128, 4);

    // L2: 8-phase GEMM -> t2, aggregate(+b2,relu) -> h2
    u16* t2 = rT;
    gemm8<false, false><<<MB256 * 2, 512, 0, stream>>>(h1, Wt2, nullptr, t2, NN, 512, 1024, 2);
    u16* h2 = rH;  // h1 dead
    k_agg<512, 1, true, true><<<NN, 64, 0, stream>>>(t2, h2, row_off, ssrc, snorm, idg, b2);

    // L3: GEMM -> g3, then fused aggregate(+b3,relu)+FC -> out
    u16* g3 = rA;  // a0 dead
    mfma_gemm<false, false><<<MB128, 256, 0, stream>>>(h2, Wt3, nullptr, g3, NN, 128, 512, 1);
    k_agg_fc<<<NN, 64, 0, stream>>>(g3, out, row_off, ssrc, snorm, idg, b3, Wfc, bfc);

    (void)in_sizes; (void)n_in; (void)out_size; (void)ws_size;
}

// Round 16
// 349.037 us; speedup vs baseline: 1.2555x; 1.2093x over previous
//
#include <hip/hip_runtime.h>
#include <hip/hip_bf16.h>
#include <cstdint>
#include <cstddef>

#define NN 50000
#define NE 400000
typedef long long i64;
typedef unsigned short u16;
typedef __attribute__((ext_vector_type(8))) short bf16x8;
typedef __attribute__((ext_vector_type(8))) unsigned short u16x8;
typedef __attribute__((ext_vector_type(4))) unsigned short u16x4;
typedef __attribute__((ext_vector_type(4))) float f32x4;

__device__ inline u16 f2bf(float f) {  // RNE
    unsigned u = __float_as_uint(f);
    u += 0x7fffu + ((u >> 16) & 1u);
    return (u16)(u >> 16);
}
__device__ inline float bf2f(u16 b) { return __uint_as_float(((unsigned)b) << 16); }

// ---------------- setup kernels ----------------
// Sampled dtype detect: 1 block, 2048 int64-views. If edge_index is int32,
// a view combines two int32s -> out of [0,NN) with overwhelming probability
// (needs every sampled high-half == 0 to fool: P ~ (1/NN)^2048). Wave-reduced
// -> <=4 same-address atomics (was 400K -> ~70us serialized; Guideline 12).
__global__ __launch_bounds__(256) void k_detect(const void* __restrict__ ei,
                                                int* __restrict__ flag) {
    int i = threadIdx.x;
    bool bad = false;
#pragma unroll
    for (int j = 0; j < 8; j++) {
        i64 v = ((const i64*)ei)[(size_t)j * 256 + i];
        bad |= (v < 0 || v >= NN);
    }
    if (__any(bad) && (i & 63) == 0) atomicOr(flag, 1);
}

__device__ inline int edge_at(const void* ei, int f32idx, int half, int i) {
    if (f32idx) return ((const int*)ei)[half * NE + i];
    return (int)((const i64*)ei)[half * NE + i];
}

__global__ void k_hist(const void* __restrict__ ei, const int* __restrict__ flag,
                       int* __restrict__ deg) {
    int i = blockIdx.x * blockDim.x + threadIdx.x;
    if (i < NE) {
        int d = edge_at(ei, *flag, 1, i);
        if ((unsigned)d < NN) atomicAdd(&deg[d], 1);
    }
}

// ---------------- 3-phase parallel scan (scan1 also does node_setup) ----------------
#define SB 256
#define NBLK ((NN + SB - 1) / SB)  // 196

__global__ __launch_bounds__(SB) void k_scan1(const int* __restrict__ deg,
                                              int* __restrict__ excl,
                                              int* __restrict__ bsum,
                                              float* __restrict__ inv_sqrt,
                                              float* __restrict__ inv_deg) {
    __shared__ int s[SB];
    int t = threadIdx.x;
    int i = blockIdx.x * SB + t;
    int v = (i < NN) ? deg[i] : 0;
    if (i < NN) {
        float d = (float)v + 1.0f;
        inv_sqrt[i] = rsqrtf(d);
        inv_deg[i]  = 1.0f / d;
    }
    s[t] = v;
    __syncthreads();
    for (int off = 1; off < SB; off <<= 1) {
        int x = (t >= off) ? s[t - off] : 0;
        __syncthreads();
        s[t] += x;
        __syncthreads();
    }
    if (i < NN) excl[i] = s[t] - v;
    if (t == SB - 1) bsum[blockIdx.x] = s[t];
}

__global__ __launch_bounds__(SB) void k_scan2(int* __restrict__ bsum) {
    __shared__ int s[SB];
    int t = threadIdx.x;
    int v = (t < NBLK) ? bsum[t] : 0;
    s[t] = v;
    __syncthreads();
    for (int off = 1; off < SB; off <<= 1) {
        int x = (t >= off) ? s[t - off] : 0;
        __syncthreads();
        s[t] += x;
        __syncthreads();
    }
    if (t < NBLK) bsum[t] = s[t] - v;
    if (t == NBLK - 1) bsum[NBLK] = s[t];
}

__global__ __launch_bounds__(SB) void k_scan3(int* __restrict__ row_off,
                                              int* __restrict__ cursor,
                                              const int* __restrict__ bsum) {
    int i = blockIdx.x * SB + threadIdx.x;
    if (i < NN) {
        int r = row_off[i] + bsum[blockIdx.x];
        row_off[i] = r;
        cursor[i]  = r;
    }
    if (i == 0) row_off[NN] = bsum[NBLK];
}

__global__ void k_scatter(const void* __restrict__ ei, const int* __restrict__ flag,
                          const float* __restrict__ inv_sqrt,
                          int* __restrict__ cursor, int* __restrict__ ssrc,
                          float* __restrict__ snorm) {
    int i = blockIdx.x * blockDim.x + threadIdx.x;
    if (i < NE) {
        int f = *flag;
        int s = edge_at(ei, f, 0, i);
        int d = edge_at(ei, f, 1, i);
        if ((unsigned)s < NN && (unsigned)d < NN) {
            int pos = atomicAdd(&cursor[d], 1);
            if ((unsigned)pos < NE) {
                ssrc[pos]  = s;
                snorm[pos] = inv_sqrt[s] * inv_sqrt[d];
            }
        }
    }
}

// ---------------- merged prep: 3x weight transpose (f32->bf16, coalesced) + x->bf16 ----------------
#define PREP_BLOCKS 6954
__global__ __launch_bounds__(256) void k_prep(const float* __restrict__ W1, u16* __restrict__ Wt1,
                                              const float* __restrict__ W2, u16* __restrict__ Wt2,
                                              const float* __restrict__ W3, u16* __restrict__ Wt3,
                                              const float* __restrict__ x, u16* __restrict__ xb) {
    __shared__ u16 tile[32][33];
    int b = blockIdx.x;
    if (b < 704) {
        const float* W; u16* Wt; int K, N, base;
        if (b < 128)      { W = W1; Wt = Wt1; K = 128;  N = 1024; base = 0; }
        else if (b < 640) { W = W2; Wt = Wt2; K = 1024; N = 512;  base = 128; }
        else              { W = W3; Wt = Wt3; K = 512;  N = 128;  base = 640; }
        int bb = b - base;
        int ntk = K >> 5;
        int tk = bb % ntk, tn = bb / ntk;
        int lx = threadIdx.x & 31, ly = threadIdx.x >> 5;
#pragma unroll
        for (int r = 0; r < 32; r += 8)
            tile[ly + r][lx] = f2bf(W[(size_t)(tk * 32 + ly + r) * N + tn * 32 + lx]);
        __syncthreads();
#pragma unroll
        for (int r = 0; r < 32; r += 8)
            Wt[(size_t)(tn * 32 + ly + r) * K + tk * 32 + lx] = tile[lx][ly + r];
    } else {
        int i = (b - 704) * 256 + threadIdx.x;
        if (i < NN * 128 / 4) {
            float4 v = ((const float4*)x)[i];
            u16x4 r;
            r[0] = f2bf(v.x); r[1] = f2bf(v.y); r[2] = f2bf(v.z); r[3] = f2bf(v.w);
            ((u16x4*)xb)[i] = r;
        }
    }
}

// ---------------- CSR aggregation (bf16 in), 4-way edge-unrolled ----------------
template <int W, int TOUT, bool BIAS, bool RELU>
__global__ __launch_bounds__(64) void k_agg(const u16* __restrict__ X, void* __restrict__ Yv,
                      const int* __restrict__ row_off, const int* __restrict__ ssrc,
                      const float* __restrict__ snorm, const float* __restrict__ inv_deg,
                      const float* __restrict__ bias) {
    constexpr int E = W / 64;
    int node = blockIdx.x;
    int lane = threadIdx.x;
    int col = lane * E;
    int beg = row_off[node], end = row_off[node + 1];
    float acc[E];
#pragma unroll
    for (int v = 0; v < E; v++) acc[v] = 0.f;

    auto rowp = [&](int srow) -> const u16* {
        unsigned s = (unsigned)srow;
        if (s >= NN) s = 0;
        return X + (size_t)s * W + col;
    };
    auto fma8 = [&](u16x8 t, float w) {
#pragma unroll
        for (int j = 0; j < 8; j++) acc[j] = fmaf(bf2f(t[j]), w, acc[j]);
    };
    auto fma2 = [&](unsigned t, float w) {
        acc[0] = fmaf(bf2f((u16)(t & 0xffff)), w, acc[0]);
        acc[1] = fmaf(bf2f((u16)(t >> 16)), w, acc[1]);
    };

    int e = beg;
    for (; e + 3 < end; e += 4) {
        int s0 = ssrc[e], s1 = ssrc[e + 1], s2 = ssrc[e + 2], s3 = ssrc[e + 3];
        float w0 = snorm[e], w1 = snorm[e + 1], w2 = snorm[e + 2], w3 = snorm[e + 3];
        w0 = ((unsigned)s0 < NN) ? w0 : 0.f;
        w1 = ((unsigned)s1 < NN) ? w1 : 0.f;
        w2 = ((unsigned)s2 < NN) ? w2 : 0.f;
        w3 = ((unsigned)s3 < NN) ? w3 : 0.f;
        if constexpr (E == 2) {
            unsigned t0 = *(const unsigned*)rowp(s0);
            unsigned t1 = *(const unsigned*)rowp(s1);
            unsigned t2 = *(const unsigned*)rowp(s2);
            unsigned t3 = *(const unsigned*)rowp(s3);
            fma2(t0, w0); fma2(t1, w1); fma2(t2, w2); fma2(t3, w3);
        } else {
            u16x8 t0 = *(const u16x8*)rowp(s0);
            u16x8 t1 = *(const u16x8*)rowp(s1);
            u16x8 t2 = *(const u16x8*)rowp(s2);
            u16x8 t3 = *(const u16x8*)rowp(s3);
            fma8(t0, w0); fma8(t1, w1); fma8(t2, w2); fma8(t3, w3);
        }
    }
    for (; e < end; e++) {
        int s = ssrc[e];
        if ((unsigned)s >= NN) continue;
        float w = snorm[e];
        if constexpr (E == 2) fma2(*(const unsigned*)rowp(s), w);
        else                  fma8(*(const u16x8*)rowp(s), w);
    }
    {   // self-loop
        float w = inv_deg[node];
        if constexpr (E == 2) fma2(*(const unsigned*)(X + (size_t)node * W + col), w);
        else                  fma8(*(const u16x8*)(X + (size_t)node * W + col), w);
    }

#pragma unroll
    for (int v = 0; v < E; v++) {
        float val = acc[v];
        if (BIAS) val += bias[col + v];
        if (RELU) val = fmaxf(val, 0.f);
        if constexpr (TOUT == 0) ((float*)Yv)[(size_t)node * W + col + v] = val;
        else ((u16*)Yv)[(size_t)node * W + col + v] = f2bf(val);
    }
}

// ---------------- final aggregation + fused FC (4-way unrolled) ----------------
__global__ __launch_bounds__(64) void k_agg_fc(const u16* __restrict__ X,
                      float* __restrict__ out,
                      const int* __restrict__ row_off, const int* __restrict__ ssrc,
                      const float* __restrict__ snorm, const float* __restrict__ inv_deg,
                      const float* __restrict__ b3, const float* __restrict__ Wfc,
                      const float* __restrict__ bfc) {
    __shared__ float hrow[128];
    int node = blockIdx.x;
    int lane = threadIdx.x;
    int col = lane * 2;
    int beg = row_off[node], end = row_off[node + 1];
    float a0 = 0.f, a1 = 0.f;

    auto rowu = [&](int srow) -> unsigned {
        unsigned s = (unsigned)srow;
        if (s >= NN) s = 0;
        return *(const unsigned*)(X + (size_t)s * 128 + col);
    };
    int e = beg;
    for (; e + 3 < end; e += 4) {
        int s0 = ssrc[e], s1 = ssrc[e + 1], s2 = ssrc[e + 2], s3 = ssrc[e + 3];
        float w0 = snorm[e], w1 = snorm[e + 1], w2 = snorm[e + 2], w3 = snorm[e + 3];
        w0 = ((unsigned)s0 < NN) ? w0 : 0.f;
        w1 = ((unsigned)s1 < NN) ? w1 : 0.f;
        w2 = ((unsigned)s2 < NN) ? w2 : 0.f;
        w3 = ((unsigned)s3 < NN) ? w3 : 0.f;
        unsigned t0 = rowu(s0), t1 = rowu(s1), t2 = rowu(s2), t3 = rowu(s3);
        a0 = fmaf(bf2f((u16)(t0 & 0xffff)), w0, a0); a1 = fmaf(bf2f((u16)(t0 >> 16)), w0, a1);
        a0 = fmaf(bf2f((u16)(t1 & 0xffff)), w1, a0); a1 = fmaf(bf2f((u16)(t1 >> 16)), w1, a1);
        a0 = fmaf(bf2f((u16)(t2 & 0xffff)), w2, a0); a1 = fmaf(bf2f((u16)(t2 >> 16)), w2, a1);
        a0 = fmaf(bf2f((u16)(t3 & 0xffff)), w3, a0); a1 = fmaf(bf2f((u16)(t3 >> 16)), w3, a1);
    }
    for (; e < end; e++) {
        int s = ssrc[e];
        if ((unsigned)s >= NN) continue;
        float w = snorm[e];
        unsigned t = *(const unsigned*)(X + (size_t)s * 128 + col);
        a0 = fmaf(bf2f((u16)(t & 0xffff)), w, a0);
        a1 = fmaf(bf2f((u16)(t >> 16)), w, a1);
    }
    {
        float w = inv_deg[node];
        unsigned t = *(const unsigned*)(X + (size_t)node * 128 + col);
        a0 = fmaf(bf2f((u16)(t & 0xffff)), w, a0);
        a1 = fmaf(bf2f((u16)(t >> 16)), w, a1);
    }
    hrow[col]     = fmaxf(a0 + b3[col], 0.f);
    hrow[col + 1] = fmaxf(a1 + b3[col + 1], 0.f);
    __syncthreads();
    if (lane < 40) {
        float s = bfc[lane];
#pragma unroll 8
        for (int k = 0; k < 128; k++)
            s = fmaf(hrow[k], Wfc[k * 40 + lane], s);
        out[(size_t)node * 40 + lane] = s;
    }
}

#define LDS_AS(p) ((__attribute__((address_space(3))) void*)(p))
#define GLB_AS(p) ((const __attribute__((address_space(1))) void*)(p))
#define EPAD 68

// ---------------- 8-phase 256x256 bf16 MFMA GEMM (L1, L2) ----------------
template <bool BIAS, bool RELU>
__global__ __launch_bounds__(512, 2) void gemm8(
    const u16* __restrict__ A, const u16* __restrict__ Bt,
    const float* __restrict__ bias, u16* __restrict__ C,
    int M, int N, int K, int nbx) {
    __shared__ __align__(16) char smem[131072];
    char* buf0 = smem;
    char* buf1 = smem + 65536;
    const int tid = threadIdx.x;
    const int lane = tid & 63;
    const int wave = tid >> 6;
    const int wm = wave >> 2;  // 0..1
    const int wn = wave & 3;   // 0..3

    const int nwg = gridDim.x;
    int lg;
    { int q = nwg >> 3, r = nwg & 7, xc = blockIdx.x & 7, pos = blockIdx.x >> 3;
      lg = (xc < r ? xc * (q + 1) : r * (q + 1) + (xc - r) * q) + pos; }
    const int bm = (lg / nbx) * 256;
    const int bn = (lg % nbx) * 256;

    f32x4 acc[8][4];
#pragma unroll
    for (int m = 0; m < 8; m++)
#pragma unroll
        for (int n = 0; n < 4; n++) acc[m][n] = (f32x4)0.f;

    const int rb = tid >> 3;
    const int csw = ((tid & 7) ^ (rb & 7)) << 4;
    const int dstA = rb * 128 + (tid & 7) * 16;
    const size_t sK = (size_t)K * 2;
    const char* Ab = (const char*)A;
    const char* Bb = (const char*)Bt;
    size_t ga[2][2], gb[2][2];
#pragma unroll
    for (int h = 0; h < 2; h++)
#pragma unroll
        for (int j = 0; j < 2; j++) {
            int ar = bm + h * 128 + j * 64 + rb; if (ar >= M) ar = M - 1;
            int br = bn + h * 128 + j * 64 + rb;
            ga[h][j] = (size_t)ar * sK + csw;
            gb[h][j] = (size_t)br * sK + csw;
        }

    auto stA = [&](char* buf, size_t kb, int h) {
        __builtin_amdgcn_global_load_lds(GLB_AS(Ab + ga[h][0] + kb), LDS_AS(buf + h * 16384 + dstA), 16, 0, 0);
        __builtin_amdgcn_global_load_lds(GLB_AS(Ab + ga[h][1] + kb), LDS_AS(buf + h * 16384 + 8192 + dstA), 16, 0, 0);
    };
    auto stB = [&](char* buf, size_t kb, int h) {
        __builtin_amdgcn_global_load_lds(GLB_AS(Bb + gb[h][0] + kb), LDS_AS(buf + 32768 + h * 16384 + dstA), 16, 0, 0);
        __builtin_amdgcn_global_load_lds(GLB_AS(Bb + gb[h][1] + kb), LDS_AS(buf + 32768 + h * 16384 + 8192 + dstA), 16, 0, 0);
    };

    const int fr = lane & 15, g = lane >> 4;
    const int ksw0 = (((0 << 2) + g) ^ (fr & 7)) << 4;
    const int ksw1 = (((1 << 2) + g) ^ (fr & 7)) << 4;
    const int aRow = (wm * 128 + fr) * 128;
    const int bRow = 32768 + (wn * 64 + fr) * 128;

    bf16x8 af[4][2], bf[4][2];
    auto LDA = [&](const char* buf, int mg) {
#pragma unroll
        for (int m = 0; m < 4; m++) {
            af[m][0] = *(const bf16x8*)(buf + aRow + mg * 8192 + m * 2048 + ksw0);
            af[m][1] = *(const bf16x8*)(buf + aRow + mg * 8192 + m * 2048 + ksw1);
        }
    };
    auto LDB = [&](const char* buf, int ng) {
#pragma unroll
        for (int n = 0; n < 2; n++) {
            bf[ng * 2 + n][0] = *(const bf16x8*)(buf + bRow + (ng * 2 + n) * 2048 + ksw0);
            bf[ng * 2 + n][1] = *(const bf16x8*)(buf + bRow + (ng * 2 + n) * 2048 + ksw1);
        }
    };
    auto QMM = [&](int mg, int ng) {
        __builtin_amdgcn_s_setprio(1);
#pragma unroll
        for (int ks = 0; ks < 2; ks++)
#pragma unroll
            for (int m = 0; m < 4; m++)
#pragma unroll
                for (int n = 0; n < 2; n++)
                    acc[mg * 4 + m][ng * 2 + n] = __builtin_amdgcn_mfma_f32_16x16x32_bf16(
                        af[m][ks], bf[ng * 2 + n][ks], acc[mg * 4 + m][ng * 2 + n], 0, 0, 0);
        __builtin_amdgcn_s_setprio(0);
    };

#define BAR  __builtin_amdgcn_s_barrier()
#define LGKM do { asm volatile("s_waitcnt lgkmcnt(0)" ::: "memory"); __builtin_amdgcn_sched_barrier(0); } while (0)

    const int nit = K >> 7;

    stB(buf0, 0, 0); stB(buf0, 0, 1);
    stA(buf0, 0, 0); stA(buf0, 0, 1);
    stB(buf1, 128, 0); stB(buf1, 128, 1);
    asm volatile("s_waitcnt vmcnt(4)" ::: "memory");
    BAR;

    for (int it2 = 0; it2 < nit; ++it2) {
        const bool lastit = (it2 == nit - 1);
        const size_t kb = (size_t)it2 * 256;
        LDA(buf0, 0); LDB(buf0, 0);
        stA(buf1, kb + 128, 0);
        BAR; LGKM; QMM(0, 0); BAR;
        LDB(buf0, 1);
        stA(buf1, kb + 128, 1);
        BAR; LGKM; QMM(0, 1); BAR;
        LDA(buf0, 1);
        if (!lastit) stB(buf0, kb + 256, 0);
        BAR; LGKM; QMM(1, 0); BAR;
        if (!lastit) stB(buf0, kb + 256, 1);
        BAR; QMM(1, 1);
        if (lastit) asm volatile("s_waitcnt vmcnt(0)" ::: "memory");
        else        asm volatile("s_waitcnt vmcnt(4)" ::: "memory");
        BAR;
        LDA(buf1, 0); LDB(buf1, 0);
        if (!lastit) stA(buf0, kb + 256, 0);
        BAR; LGKM; QMM(0, 0); BAR;
        LDB(buf1, 1);
        if (!lastit) stA(buf0, kb + 256, 1);
        BAR; LGKM; QMM(0, 1); BAR;
        LDA(buf1, 1);
        if (!lastit) stB(buf1, kb + 384, 0);
        BAR; LGKM; QMM(1, 0); BAR;
        if (!lastit) stB(buf1, kb + 384, 1);
        BAR; QMM(1, 1);
        if (!lastit) asm volatile("s_waitcnt vmcnt(4)" ::: "memory");
        BAR;
    }

    u16* Es = (u16*)(smem + (size_t)wave * (64 * EPAD * 2));
    const int cr = (lane >> 4) << 2;
    const int cc = lane & 15;
    const int rl = lane >> 3;
    const int c8 = (lane & 7) * 8;
#pragma unroll
    for (int pass = 0; pass < 2; pass++) {
#pragma unroll
        for (int n = 0; n < 4; n++) {
            float bv = BIAS ? bias[bn + wn * 64 + n * 16 + cc] : 0.f;
#pragma unroll
            for (int m = 0; m < 4; m++) {
#pragma unroll
                for (int j = 0; j < 4; j++) {
                    float v = acc[pass * 4 + m][n][j] + bv;
                    if (RELU) v = fmaxf(v, 0.f);
                    Es[(m * 16 + cr + j) * EPAD + n * 16 + cc] = f2bf(v);
                }
            }
        }
#pragma unroll
        for (int itr = 0; itr < 8; itr++) {
            int lr = itr * 8 + rl;
            u16x8 vv = *(const u16x8*)(Es + lr * EPAD + c8);
            int grow = bm + wm * 128 + pass * 64 + lr;
            if (grow < M)
                *(u16x8*)(C + (size_t)grow * N + bn + wn * 64 + c8) = vv;
        }
    }
#undef BAR
#undef LGKM
}

// ---------------- 128x128 bf16 MFMA GEMM, BK=64 (L3, N=128) ----------------
#define GBM 128
#define GBN 128
#define GBK 64

template <bool BIAS, bool RELU>
__global__ __launch_bounds__(256) void mfma_gemm(
    const u16* __restrict__ A, const u16* __restrict__ Bt,
    const float* __restrict__ bias, u16* __restrict__ C,
    int M, int N, int K, int nbx) {
    __shared__ __align__(16) char smem[4 * 64 * EPAD * 2];
    u16* As = (u16*)smem;
    u16* Bs = (u16*)(smem + 16384);
    const int tid = threadIdx.x;
    const int lane = tid & 63;
    const int wave = tid >> 6;
    const int wr = wave >> 1, wc = wave & 1;

    const int nwg = gridDim.x;
    int lg;
    { int q = nwg >> 3, r = nwg & 7, xc = blockIdx.x & 7, pos = blockIdx.x >> 3;
      lg = (xc < r ? xc * (q + 1) : r * (q + 1) + (xc - r) * q) + pos; }
    const int bm = (lg / nbx) * GBM;
    const int bn = (lg % nbx) * GBN;

    f32x4 acc[4][4];
#pragma unroll
    for (int m = 0; m < 4; m++)
#pragma unroll
        for (int n = 0; n < 4; n++) acc[m][n] = (f32x4)0.f;

    const int rbase = tid >> 3;
    const int csw = (((tid & 7) ^ (rbase & 7)) << 4);
    const size_t sK = (size_t)K * 2;
    const char* Ab = (const char*)A;
    const char* Bb = (const char*)Bt;
    size_t ga[4], gb[4];
#pragma unroll
    for (int i = 0; i < 4; i++) {
        int r0 = rbase + 32 * i;
        int ar = bm + r0; if (ar >= M) ar = M - 1;
        int br = bn + r0; if (br >= N) br = N - 1;
        ga[i] = (size_t)ar * sK + csw;
        gb[i] = (size_t)br * sK + csw;
    }
    const int od = tid * 16;

    const int fr = lane & 15, g = lane >> 4;
    int aoff[2][4], boff[2][4];
#pragma unroll
    for (int ks = 0; ks < 2; ks++) {
        const int sw = (((ks << 2) + g) ^ (fr & 7)) << 4;
#pragma unroll
        for (int m = 0; m < 4; m++) {
            aoff[ks][m] = (wr * 64 + m * 16 + fr) * 128 + sw;
            boff[ks][m] = (wc * 64 + m * 16 + fr) * 128 + sw;
        }
    }

    for (int k0 = 0; k0 < K; k0 += GBK) {
        const size_t kb = (size_t)k0 * 2;
#pragma unroll
        for (int i = 0; i < 4; i++) {
            __builtin_amdgcn_global_load_lds(GLB_AS(Ab + ga[i] + kb), LDS_AS((char*)As + od + i * 4096), 16, 0, 0);
            __builtin_amdgcn_global_load_lds(GLB_AS(Bb + gb[i] + kb), LDS_AS((char*)Bs + od + i * 4096), 16, 0, 0);
        }
        __syncthreads();
#pragma unroll
        for (int ks = 0; ks < 2; ks++) {
            bf16x8 af[4], bfr[4];
#pragma unroll
            for (int n = 0; n < 4; n++) bfr[n] = *(const bf16x8*)((char*)Bs + boff[ks][n]);
#pragma unroll
            for (int m = 0; m < 4; m++) af[m] = *(const bf16x8*)((char*)As + aoff[ks][m]);
#pragma unroll
            for (int m = 0; m < 4; m++)
#pragma unroll
                for (int n = 0; n < 4; n++)
                    acc[m][n] = __builtin_amdgcn_mfma_f32_16x16x32_bf16(af[m], bfr[n], acc[m][n], 0, 0, 0);
        }
        __syncthreads();
    }

    u16* Es = (u16*)smem + (size_t)wave * 64 * EPAD;
    const int cr = (lane >> 4) << 2;
    const int cc = lane & 15;
#pragma unroll
    for (int n = 0; n < 4; n++) {
        float bv = BIAS ? bias[bn + wc * 64 + n * 16 + cc] : 0.f;
#pragma unroll
        for (int m = 0; m < 4; m++) {
#pragma unroll
            for (int j = 0; j < 4; j++) {
                float v = acc[m][n][j] + bv;
                if (RELU) v = fmaxf(v, 0.f);
                Es[(m * 16 + cr + j) * EPAD + n * 16 + cc] = f2bf(v);
            }
        }
    }
    const int rl = lane >> 3;
    const int c8 = (lane & 7) * 8;
#pragma unroll
    for (int it = 0; it < 8; it++) {
        int lr = it * 8 + rl;
        u16x8 vv = *(const u16x8*)(Es + lr * EPAD + c8);
        int grow = bm + wr * 64 + lr;
        if (grow < M)
            *(u16x8*)(C + (size_t)grow * N + bn + wc * 64 + c8) = vv;
    }
}

// ---------------- launch ----------------
extern "C" void kernel_launch(void* const* d_in, const int* in_sizes, int n_in,
                              void* d_out, int out_size, void* d_ws, size_t ws_size,
                              hipStream_t stream) {
    const float* x   = (const float*)d_in[0];
    const void*  ei  = d_in[1];
    const float* W1  = (const float*)d_in[2];
    const float* b1  = (const float*)d_in[3];
    const float* W2  = (const float*)d_in[4];
    const float* b2  = (const float*)d_in[5];
    const float* W3  = (const float*)d_in[6];
    const float* b3  = (const float*)d_in[7];
    const float* Wfc = (const float*)d_in[8];
    const float* bfc = (const float*)d_in[9];
    float* out = (float*)d_out;

    char* ws = (char*)d_ws;
    size_t off = 0;
    auto take = [&](size_t bytes) -> void* {
        off = (off + 255) & ~(size_t)255;
        void* p = ws + off;
        off += bytes;
        return p;
    };
    int*   deg     = (int*)take((size_t)NN * 4);
    int*   row_off = (int*)take((size_t)(NN + 1) * 4);
    int*   cursor  = (int*)take((size_t)NN * 4);
    float* isq     = (float*)take((size_t)NN * 4);
    float* idg     = (float*)take((size_t)NN * 4);
    int*   ssrc    = (int*)take((size_t)NE * 4);
    float* snorm   = (float*)take((size_t)NE * 4);
    int*   flag    = (int*)take(256);
    int*   bsum    = (int*)take((size_t)(NBLK + 1) * 4);
    u16*   Wt1     = (u16*)take((size_t)1024 * 128 * 2);
    u16*   Wt2     = (u16*)take((size_t)512 * 1024 * 2);
    u16*   Wt3     = (u16*)take((size_t)128 * 512 * 2);
    u16*   xbf     = (u16*)take((size_t)NN * 128 * 2);   // bf16 x
    u16*   rA      = (u16*)take((size_t)NN * 128 * 2);   // a0, later g3
    u16*   rH      = (u16*)take((size_t)NN * 1024 * 2);  // h1, later h2
    u16*   rT      = (u16*)take((size_t)NN * 512 * 2);   // t2

    // zero deg + flag via async memset (graph-capturable)
    hipMemsetAsync(deg, 0, (size_t)NN * 4, stream);
    hipMemsetAsync(flag, 0, 4, stream);

    // merged prep (weights + x conversion) — independent of graph setup
    k_prep<<<PREP_BLOCKS, 256, 0, stream>>>(W1, Wt1, W2, Wt2, W3, Wt3, x, xbf);

    // graph setup (sampled dtype detect: 1 block, <=4 atomics)
    k_detect<<<1, 256, 0, stream>>>(ei, flag);
    k_hist<<<(NE + 255) / 256, 256, 0, stream>>>(ei, flag, deg);
    k_scan1<<<NBLK, SB, 0, stream>>>(deg, row_off, bsum, isq, idg);
    k_scan2<<<1, SB, 0, stream>>>(bsum);
    k_scan3<<<NBLK, SB, 0, stream>>>(row_off, cursor, bsum);
    k_scatter<<<(NE + 255) / 256, 256, 0, stream>>>(ei, flag, isq, cursor, ssrc, snorm);

    const int MB256 = (NN + 255) / 256;  // 196
    const int MB128 = (NN + 127) / 128;  // 391

    // L1: aggregate bf16 x, 8-phase GEMM(+b1,relu) -> h1
    u16* a0 = rA;
    k_agg<128, 1, false, false><<<NN, 64, 0, stream>>>(xbf, a0, row_off, ssrc, snorm, idg, nullptr);
    u16* h1 = rH;
    gemm8<true, true><<<MB256 * 4, 512, 0, stream>>>(a0, Wt1, b1, h1, NN, 1024, 128, 4);

    // L2: 8-phase GEMM -> t2, aggregate(+b2,relu) -> h2
    u16* t2 = rT;
    gemm8<false, false><<<MB256 * 2, 512, 0, stream>>>(h1, Wt2, nullptr, t2, NN, 512, 1024, 2);
    u16* h2 = rH;  // h1 dead
    k_agg<512, 1, true, true><<<NN, 64, 0, stream>>>(t2, h2, row_off, ssrc, snorm, idg, b2);

    // L3: GEMM -> g3, then fused aggregate(+b3,relu)+FC -> out
    u16* g3 = rA;  // a0 dead
    mfma_gemm<false, false><<<MB128, 256, 0, stream>>>(h2, Wt3, nullptr, g3, NN, 128, 512, 1);
    k_agg_fc<<<NN, 64, 0, stream>>>(g3, out, row_off, ssrc, snorm, idg, b3, Wfc, bfc);

    (void)in_sizes; (void)n_in; (void)out_size; (void)ws_size;
}